// Round 8
// baseline (377.985 us; speedup 1.0000x reference)
//
#include <hip/hip_runtime.h>
#include <hip/hip_bf16.h>

#define N_PAPER 100000
#define N_LABEL 128
#define E_CITES 1600000
#define E_IS    100000
#define NBKT    98   // node>>10 buckets
#define A2_CHUNK 2048
#define LSPLIT  8

typedef __bf16 bf16x8 __attribute__((ext_vector_type(8)));
typedef float  f32x4  __attribute__((ext_vector_type(4)));

static __device__ __forceinline__ float bf_lo(unsigned u) {
    union { unsigned u; float f; } v; v.u = u << 16; return v.f;
}
static __device__ __forceinline__ float bf_hi(unsigned u) {
    union { unsigned u; float f; } v; v.u = u & 0xffff0000u; return v.f;
}
static __device__ __forceinline__ unsigned pk_bf(float a, float b) {
    __hip_bfloat16 x = __float2bfloat16(a), y = __float2bfloat16(b);
    unsigned short ux = *(unsigned short*)&x, uy = *(unsigned short*)&y;
    return (unsigned)ux | ((unsigned)uy << 16);
}

// ---------------- fused bucket histograms (cites, rev, label) ----------------
#define NCC 224
#define NCR 32
#define NCL 32
__global__ __launch_bounds__(256) void fused_count(
    const int* __restrict__ cd, const int* __restrict__ iss, const int* __restrict__ isd,
    int* __restrict__ bhist_c, int* __restrict__ bhist_r, int* __restrict__ bhist_l)
{
    __shared__ int h[128];
    int b = blockIdx.x, t = threadIdx.x;
    const int* key; int E, shift, nb, b0, nblk; int* hist;
    if (b < NCC)            { key = cd;  E = E_CITES; hist = bhist_c; shift = 10; nb = NBKT; b0 = b;             nblk = NCC; }
    else if (b < NCC + NCR) { key = iss; E = E_IS;    hist = bhist_r; shift = 10; nb = NBKT; b0 = b - NCC;       nblk = NCR; }
    else                    { key = isd; E = E_IS;    hist = bhist_l; shift = 0;  nb = 128;  b0 = b - NCC - NCL; nblk = NCL; }
    if (t < nb) h[t] = 0;
    __syncthreads();
    for (int i = b0 * 256 + t; i < E; i += nblk * 256)
        atomicAdd(&h[key[i] >> shift], 1);
    __syncthreads();
    if (t < nb && h[t]) atomicAdd(&hist[t], h[t]);
}

// single block: exclusive-scan three histograms (cites 98, rev 98, label 128)
__global__ __launch_bounds__(128) void scan_sums(
    const int* __restrict__ bhist_c, int* __restrict__ bbase_c, int* __restrict__ bcur_c,
    const int* __restrict__ bhist_r, int* __restrict__ bbase_r, int* __restrict__ bcur_r,
    const int* __restrict__ bhist_l, int* __restrict__ rp_l, int* __restrict__ bcur_l)
{
    __shared__ int sh[3][128];
    int t = threadIdx.x;
    sh[0][t] = (t < NBKT) ? bhist_c[t] : 0;
    sh[1][t] = (t < NBKT) ? bhist_r[t] : 0;
    sh[2][t] = bhist_l[t];
    __syncthreads();
    for (int off = 1; off < 128; off <<= 1) {
        int v0 = (t >= off) ? sh[0][t - off] : 0;
        int v1 = (t >= off) ? sh[1][t - off] : 0;
        int v2 = (t >= off) ? sh[2][t - off] : 0;
        __syncthreads();
        sh[0][t] += v0; sh[1][t] += v1; sh[2][t] += v2;
        __syncthreads();
    }
    if (t < NBKT) {
        int b = (t == 0) ? 0 : sh[0][t - 1];
        bbase_c[t] = b; bcur_c[t] = b;
        if (t == NBKT - 1) bbase_c[NBKT] = sh[0][t];
        int b2 = (t == 0) ? 0 : sh[1][t - 1];
        bbase_r[t] = b2; bcur_r[t] = b2;
        if (t == NBKT - 1) bbase_r[NBKT] = sh[1][t];
    }
    int b3 = (t == 0) ? 0 : sh[2][t - 1];
    rp_l[t] = b3; bcur_l[t] = b3;
    if (t == 127) rp_l[128] = sh[2][127];
}

// ---------------- fused bucketed edge scatter (packed u32) ----------------
// ebuf[p] = ((key & 1023) << 17) | val   (val < 2^17)
#define NSC ((E_CITES + A2_CHUNK - 1) / A2_CHUNK)
#define NSI ((E_IS + A2_CHUNK - 1) / A2_CHUNK)
__global__ __launch_bounds__(256) void fused_scatter(
    const int* __restrict__ cd, const int* __restrict__ cs,
    const int* __restrict__ iss, const int* __restrict__ isd,
    int* __restrict__ bcur_c, unsigned* __restrict__ ebuf_c,
    int* __restrict__ bcur_r, unsigned* __restrict__ ebuf_r,
    int* __restrict__ bcur_l, unsigned* __restrict__ ebuf_l)
{
    __shared__ int sk[A2_CHUNK], sv[A2_CHUNK];
    __shared__ int h[128], base[128], cur[128];
    int b = blockIdx.x, t = threadIdx.x;
    const int* key; const int* val; int E, shift, b0; int* bcur; unsigned* ebuf;
    if (b < NSC)            { key = cd;  val = cs;  E = E_CITES; bcur = bcur_c; ebuf = ebuf_c; shift = 10; b0 = b; }
    else if (b < NSC + NSI) { key = iss; val = isd; E = E_IS;    bcur = bcur_r; ebuf = ebuf_r; shift = 10; b0 = b - NSC; }
    else                    { key = isd; val = iss; E = E_IS;    bcur = bcur_l; ebuf = ebuf_l; shift = 0;  b0 = b - NSC - NSI; }
    int e0 = b0 * A2_CHUNK;
    int n = min(A2_CHUNK, E - e0);
    for (int i = t; i < 128; i += 256) h[i] = 0;
    __syncthreads();
    for (int i = t; i < n; i += 256) {
        int k = key[e0 + i], v = val[e0 + i];
        sk[i] = k; sv[i] = v;
        atomicAdd(&h[k >> shift], 1);
    }
    __syncthreads();
    for (int i = t; i < 128; i += 256) { base[i] = atomicAdd(&bcur[i], h[i]); cur[i] = 0; }
    __syncthreads();
    for (int i = t; i < n; i += 256) {
        int bb = sk[i] >> shift;
        int p = base[bb] + atomicAdd(&cur[bb], 1);
        ebuf[p] = ((unsigned)(sk[i] & 1023) << 17) | (unsigned)sv[i];
    }
}

// ---------------- fused per-bucket CSR build (cites + rev) ----------------
__global__ __launch_bounds__(1024) void fused_csr(
    const unsigned* __restrict__ ebuf_c, const int* __restrict__ bbase_c,
    int* __restrict__ rp_c, int* __restrict__ col_c, float* __restrict__ dinv,
    const unsigned* __restrict__ ebuf_r, const int* __restrict__ bbase_r,
    int* __restrict__ rp_r, int* __restrict__ col_r)
{
    __shared__ int hist[1024];
    __shared__ int sc[1024];
    int bb = blockIdx.x, t = threadIdx.x;
    const unsigned* ebuf; const int* bbase; int* rp; int* col; float* dv; int b;
    if (bb < NBKT) { ebuf = ebuf_c; bbase = bbase_c; rp = rp_c; col = col_c; dv = dinv; b = bb; }
    else           { ebuf = ebuf_r; bbase = bbase_r; rp = rp_r; col = col_r; dv = nullptr; b = bb - NBKT; }
    int s = bbase[b], e = bbase[b + 1];
    hist[t] = 0;
    __syncthreads();
    for (int i = s + t; i < e; i += 1024)
        atomicAdd(&hist[ebuf[i] >> 17], 1);
    __syncthreads();
    int v = hist[t];
    sc[t] = v;
    __syncthreads();
    for (int off = 1; off < 1024; off <<= 1) {
        int u = (t >= off) ? sc[t - off] : 0;
        __syncthreads();
        sc[t] += u;
        __syncthreads();
    }
    int excl = sc[t] - v;
    int node = b * 1024 + t;
    if (node < N_PAPER) {
        rp[node] = s + excl;
        if (dv) dv[node] = rsqrtf((float)v + 1.0f);
        if (node == N_PAPER - 1) rp[N_PAPER] = s + excl + v;
    }
    __syncthreads();
    hist[t] = s + excl;   // reuse as running cursor
    __syncthreads();
    for (int i = s + t; i < e; i += 1024) {
        unsigned u = ebuf[i];
        int p = atomicAdd(&hist[u >> 17], 1);
        col[p] = (int)(u & 0x1FFFFu);
    }
}

// ---------------- fused prep: conv_bf16 + pack_wp(1,2) + yrev1 small_mm -----
#define NCONV 12500   // 100000*128/4 / 256
__global__ __launch_bounds__(256) void fused_prep(
    const float* __restrict__ xp, __hip_bfloat16* __restrict__ xp_bf,
    const float* __restrict__ g1, const float* __restrict__ r1, __hip_bfloat16* __restrict__ Wp1,
    const float* __restrict__ g2, const float* __restrict__ r2, __hip_bfloat16* __restrict__ Wp2,
    const float* __restrict__ xl, const float* __restrict__ W1rev, float* __restrict__ yrev1)
{
    int b = blockIdx.x, t = threadIdx.x;
    if (b < NCONV) {
        int i = b * 256 + t;
        const int n4 = N_PAPER * 128 / 4;
        if (i < n4) {
            float4 v = *(const float4*)(xp + (size_t)i * 4);
            __hip_bfloat16* o = xp_bf + (size_t)i * 4;
            o[0] = __float2bfloat16(v.x); o[1] = __float2bfloat16(v.y);
            o[2] = __float2bfloat16(v.z); o[3] = __float2bfloat16(v.w);
        }
        return;
    }
    if (b < NCONV + 128 + 64) {
        bool big = (b < NCONV + 128);
        const float* g = big ? g1 : g2;
        const float* r = big ? r1 : r2;
        __hip_bfloat16* Wp = big ? Wp1 : Wp2;
        int DG = big ? 128 : 64;
        int i = (big ? (b - NCONV) : (b - NCONV - 128)) * 256 + t;
        int j    = i & 7;
        int lane = (i >> 3) & 63;
        int ks   = (i >> 9) & 3;
        int nt   = i >> 11;
        int k = ks * 32 + (lane >> 4) * 8 + j;
        int c = nt * 16 + (lane & 15);
        float v = (c < DG) ? g[k * DG + c] : r[k * DG + (c - DG)];
        Wp[i] = __float2bfloat16(v);
        return;
    }
    // yrev1: 64 blocks, 2 labels per block
    __shared__ float xrow[2][128];
    int bb = b - (NCONV + 128 + 64);
    int half = t >> 7, tt = t & 127;
    int l = bb * 2 + half;
    xrow[half][tt] = xl[(size_t)l * 128 + tt];
    __syncthreads();
    float o = 0.f;
    for (int k = 0; k < 128; ++k) o = fmaf(xrow[half][k], W1rev[k * 128 + tt], o);
    yrev1[(size_t)l * 128 + tt] = o;
}

// ---------------- MFMA GEMM: Hg = dinv.*(A@Wg), Hr = A@Wr  (bf16) ----------
template<int DG>
__global__ __launch_bounds__(256) void gemm_mfma(
    const __hip_bfloat16* __restrict__ A, const __hip_bfloat16* __restrict__ Wp,
    const float* __restrict__ dinv,
    __hip_bfloat16* __restrict__ Hg, __hip_bfloat16* __restrict__ Hr, int M)
{
    constexpr int NT2 = 2 * DG / 16;
    int tid = threadIdx.x;
    int wv = tid >> 6, lane = tid & 63;
    int m0 = blockIdx.x * 64 + wv * 16;
    int row = m0 + (lane & 15);
    int rowc = min(row, M - 1);
    int kg = lane >> 4;

    bf16x8 a[4];
    const __hip_bfloat16* ap = A + (size_t)rowc * 128 + kg * 8;
    #pragma unroll
    for (int ks = 0; ks < 4; ++ks)
        a[ks] = *(const bf16x8*)(ap + ks * 32);

    f32x4 acc[NT2] = {};
    #pragma unroll
    for (int ks = 0; ks < 4; ++ks) {
        #pragma unroll
        for (int nt = 0; nt < NT2; ++nt) {
            bf16x8 b = *(const bf16x8*)(Wp + ((size_t)(nt * 4 + ks) * 64 + lane) * 8);
            acc[nt] = __builtin_amdgcn_mfma_f32_16x16x32_bf16(a[ks], b, acc[nt], 0, 0, 0);
        }
    }

    int rbase = m0 + (lane >> 4) * 4;
    int c = lane & 15;
    float ds[4];
    #pragma unroll
    for (int r = 0; r < 4; ++r) {
        int rr = rbase + r;
        ds[r] = (rr < M) ? dinv[rr] : 1.f;
    }
    #pragma unroll
    for (int nt = 0; nt < NT2; ++nt) {
        bool isG = (nt < DG / 16);
        __hip_bfloat16* dst = isG ? Hg : Hr;
        int cc = isG ? (nt * 16 + c) : ((nt - DG / 16) * 16 + c);
        #pragma unroll
        for (int r = 0; r < 4; ++r) {
            int rr = rbase + r;
            float v = isG ? acc[nt][r] * ds[r] : acc[nt][r];
            if (rr < M) dst[(size_t)rr * DG + cc] = __float2bfloat16(v);
        }
    }
}

// ---------------- fused paper-side assembly (bf16 H, Hg pre-scaled) ---------
// Per wave: 4 groups of 16 lanes; group g owns a CONTIGUOUS quarter of the
// node's edge list, 4-way unrolled -> up to 16 independent row loads in flight.
template<int D, bool RELU, typename OutT>
__global__ __launch_bounds__(256) void paper_assemble(
    const __hip_bfloat16* __restrict__ Hg, const __hip_bfloat16* __restrict__ Hr,
    const int* __restrict__ rp_c, const int* __restrict__ col_c,
    const float* __restrict__ dinv,
    const int* __restrict__ rp_r, const int* __restrict__ col_r,
    const float* __restrict__ yrev,
    const float* __restrict__ gcn_b, const float* __restrict__ rev_relb,
    OutT* __restrict__ out)
{
    constexpr int NB = D / 16;  // dims per lane: 8 (D=128) or 4 (D=64)
    int w = (int)((blockIdx.x * 256 + threadIdx.x) >> 6);
    if (w >= N_PAPER) return;
    int lane = threadIdx.x & 63;
    int grp = lane >> 4, sub = lane & 15;
    int d0 = sub * NB;

    // ---- early independent loads (overlap the gather latency) ----
    int2 se  = *(const int2*)(rp_c + w);
    int2 se2 = *(const int2*)(rp_r + w);
    float di = dinv[w];
    const __hip_bfloat16* hg = Hg + (size_t)w * D + d0;
    const __hip_bfloat16* hr = Hr + (size_t)w * D + d0;
    uint4 ug4, ur4; uint2 ug2, ur2;
    if constexpr (NB == 8) { ug4 = *(const uint4*)hg; ur4 = *(const uint4*)hr; }
    else                   { ug2 = *(const uint2*)hg; ur2 = *(const uint2*)hr; }
    float bsum[NB];
    #pragma unroll
    for (int k = 0; k < NB; ++k) bsum[k] = gcn_b[d0 + k] + rev_relb[d0 + k];

    // ---- edge gather: contiguous quarter per group, unroll 4 ----
    int s = se.x, e = se.y;
    int q = ((e - s) + 3) >> 2;
    int j  = s + grp * q;
    int j1 = min(j + q, e);
    float acc[NB] = {};
    for (; j + 3 < j1; j += 4) {
        int c0 = col_c[j], c1 = col_c[j + 1], c2 = col_c[j + 2], c3 = col_c[j + 3];
        if constexpr (NB == 8) {
            uint4 u0 = *(const uint4*)(Hg + (size_t)c0 * D + d0);
            uint4 u1 = *(const uint4*)(Hg + (size_t)c1 * D + d0);
            uint4 u2 = *(const uint4*)(Hg + (size_t)c2 * D + d0);
            uint4 u3 = *(const uint4*)(Hg + (size_t)c3 * D + d0);
            acc[0] += (bf_lo(u0.x) + bf_lo(u1.x)) + (bf_lo(u2.x) + bf_lo(u3.x));
            acc[1] += (bf_hi(u0.x) + bf_hi(u1.x)) + (bf_hi(u2.x) + bf_hi(u3.x));
            acc[2] += (bf_lo(u0.y) + bf_lo(u1.y)) + (bf_lo(u2.y) + bf_lo(u3.y));
            acc[3] += (bf_hi(u0.y) + bf_hi(u1.y)) + (bf_hi(u2.y) + bf_hi(u3.y));
            acc[4] += (bf_lo(u0.z) + bf_lo(u1.z)) + (bf_lo(u2.z) + bf_lo(u3.z));
            acc[5] += (bf_hi(u0.z) + bf_hi(u1.z)) + (bf_hi(u2.z) + bf_hi(u3.z));
            acc[6] += (bf_lo(u0.w) + bf_lo(u1.w)) + (bf_lo(u2.w) + bf_lo(u3.w));
            acc[7] += (bf_hi(u0.w) + bf_hi(u1.w)) + (bf_hi(u2.w) + bf_hi(u3.w));
        } else {
            uint2 u0 = *(const uint2*)(Hg + (size_t)c0 * D + d0);
            uint2 u1 = *(const uint2*)(Hg + (size_t)c1 * D + d0);
            uint2 u2 = *(const uint2*)(Hg + (size_t)c2 * D + d0);
            uint2 u3 = *(const uint2*)(Hg + (size_t)c3 * D + d0);
            acc[0] += (bf_lo(u0.x) + bf_lo(u1.x)) + (bf_lo(u2.x) + bf_lo(u3.x));
            acc[1] += (bf_hi(u0.x) + bf_hi(u1.x)) + (bf_hi(u2.x) + bf_hi(u3.x));
            acc[2] += (bf_lo(u0.y) + bf_lo(u1.y)) + (bf_lo(u2.y) + bf_lo(u3.y));
            acc[3] += (bf_hi(u0.y) + bf_hi(u1.y)) + (bf_hi(u2.y) + bf_hi(u3.y));
        }
    }
    for (; j < j1; ++j) {
        int src = col_c[j];
        const __hip_bfloat16* p = Hg + (size_t)src * D + d0;
        if constexpr (NB == 8) {
            uint4 u = *(const uint4*)p;
            acc[0] += bf_lo(u.x); acc[1] += bf_hi(u.x);
            acc[2] += bf_lo(u.y); acc[3] += bf_hi(u.y);
            acc[4] += bf_lo(u.z); acc[5] += bf_hi(u.z);
            acc[6] += bf_lo(u.w); acc[7] += bf_hi(u.w);
        } else {
            uint2 u = *(const uint2*)p;
            acc[0] += bf_lo(u.x); acc[1] += bf_hi(u.x);
            acc[2] += bf_lo(u.y); acc[3] += bf_hi(u.y);
        }
    }
    #pragma unroll
    for (int k = 0; k < NB; ++k) {
        acc[k] += __shfl_xor(acc[k], 16);
        acc[k] += __shfl_xor(acc[k], 32);
    }
    if (grp != 0) return;

    float res[NB];
    if constexpr (NB == 8) {
        float sg[8] = { bf_lo(ug4.x), bf_hi(ug4.x), bf_lo(ug4.y), bf_hi(ug4.y),
                        bf_lo(ug4.z), bf_hi(ug4.z), bf_lo(ug4.w), bf_hi(ug4.w) };
        float sr[8] = { bf_lo(ur4.x), bf_hi(ur4.x), bf_lo(ur4.y), bf_hi(ur4.y),
                        bf_lo(ur4.z), bf_hi(ur4.z), bf_lo(ur4.w), bf_hi(ur4.w) };
        #pragma unroll
        for (int k = 0; k < 8; ++k)
            res[k] = di * (acc[k] + sg[k]) + sr[k] + bsum[k];
    } else {
        float sg[4] = { bf_lo(ug2.x), bf_hi(ug2.x), bf_lo(ug2.y), bf_hi(ug2.y) };
        float sr[4] = { bf_lo(ur2.x), bf_hi(ur2.x), bf_lo(ur2.y), bf_hi(ur2.y) };
        #pragma unroll
        for (int k = 0; k < 4; ++k)
            res[k] = di * (acc[k] + sg[k]) + sr[k] + bsum[k];
    }
    for (int jj = se2.x; jj < se2.y; ++jj) {
        const float* yr = yrev + (size_t)col_r[jj] * D + d0;
        #pragma unroll
        for (int k = 0; k < NB; ++k) res[k] += yr[k];
    }
    #pragma unroll
    for (int k = 0; k < NB; ++k) {
        res[k] *= 0.5f;
        if (RELU) res[k] = fmaxf(res[k], 0.f);
    }
    if constexpr (sizeof(OutT) == 2) {
        if constexpr (NB == 8) {
            uint4 o = make_uint4(pk_bf(res[0], res[1]), pk_bf(res[2], res[3]),
                                 pk_bf(res[4], res[5]), pk_bf(res[6], res[7]));
            *(uint4*)(out + (size_t)w * D + d0) = o;
        } else {
            uint2 o = make_uint2(pk_bf(res[0], res[1]), pk_bf(res[2], res[3]));
            *(uint2*)(out + (size_t)w * D + d0) = o;
        }
    } else {
        if constexpr (NB == 8) {
            *(float4*)((float*)out + (size_t)w * D + d0) =
                make_float4(res[0], res[1], res[2], res[3]);
            *(float4*)((float*)out + (size_t)w * D + d0 + 4) =
                make_float4(res[4], res[5], res[6], res[7]);
        } else {
            *(float4*)((float*)out + (size_t)w * D + d0) =
                make_float4(res[0], res[1], res[2], res[3]);
        }
    }
}

// ---------------- label-side aggregation (grid: 128 labels x LSPLIT) --------
__global__ __launch_bounds__(128) void label_agg(
    const __hip_bfloat16* __restrict__ Xsrc,
    const int* __restrict__ rp_l, const unsigned* __restrict__ ebuf_l,
    float* __restrict__ partialL)
{
    int l = blockIdx.x, sp = blockIdx.y, t = threadIdx.x;
    int s = rp_l[l], e = rp_l[l + 1];
    int n = e - s;
    int per = (n + LSPLIT - 1) / LSPLIT;
    int b = s + sp * per;
    int en = min(b + per, e);
    float acc = 0.f;
    for (int m = b; m < en; ++m)
        acc += __bfloat162float(Xsrc[(size_t)(ebuf_l[m] & 0x1FFFFu) * 128 + t]);
    partialL[((size_t)l * LSPLIT + sp) * 128 + t] = acc;
}

// ---------------- label-side finish: sum partials + tiny GEMM (+ yrev2) -----
template<int DOUT, bool RELU, bool YREV2>
__global__ __launch_bounds__(128) void label_finish(
    const float* __restrict__ partialL, const float* __restrict__ Xdst,
    const float* __restrict__ relW, const float* __restrict__ rootW,
    const float* __restrict__ relb, float* __restrict__ out,
    const float* __restrict__ W2rev, float* __restrict__ yrev2)
{
    __shared__ float arow[128];
    __shared__ float xrow[128];
    __shared__ float hrow[128];
    int l = blockIdx.x, t = threadIdx.x;
    float a = 0.f;
    #pragma unroll
    for (int sp = 0; sp < LSPLIT; ++sp)
        a += partialL[((size_t)l * LSPLIT + sp) * 128 + t];
    arow[t] = a;
    xrow[t] = Xdst[(size_t)l * 128 + t];
    __syncthreads();
    float o = 0.f;
    if (t < DOUT) {
        o = relb[t];
        for (int k = 0; k < 128; ++k)
            o = fmaf(arow[k], relW[k * DOUT + t], fmaf(xrow[k], rootW[k * DOUT + t], o));
        if (RELU) o = fmaxf(o, 0.f);
        out[(size_t)l * DOUT + t] = o;
    }
    if constexpr (YREV2) {
        hrow[t] = o;           // DOUT == 128 here
        __syncthreads();
        if (t < 64) {
            float y = 0.f;
            for (int k = 0; k < 128; ++k)
                y = fmaf(hrow[k], W2rev[k * 64 + t], y);
            yrev2[(size_t)l * 64 + t] = y;
        }
    }
}

extern "C" void kernel_launch(void* const* d_in, const int* in_sizes, int n_in,
                              void* d_out, int out_size, void* d_ws, size_t ws_size,
                              hipStream_t stream)
{
    const float* xp          = (const float*)d_in[0];
    const float* xl          = (const float*)d_in[1];
    const int*   cs          = (const int*)d_in[2];
    const int*   cd          = (const int*)d_in[3];
    const int*   iss         = (const int*)d_in[4];
    const int*   isd         = (const int*)d_in[5];
    const float* l1_gcn_W    = (const float*)d_in[6];
    const float* l1_gcn_b    = (const float*)d_in[7];
    const float* l1_is_relW  = (const float*)d_in[8];
    const float* l1_is_relb  = (const float*)d_in[9];
    const float* l1_is_rootW = (const float*)d_in[10];
    const float* l1_rev_relW = (const float*)d_in[11];
    const float* l1_rev_relb = (const float*)d_in[12];
    const float* l1_rev_rootW= (const float*)d_in[13];
    const float* l2_gcn_W    = (const float*)d_in[14];
    const float* l2_gcn_b    = (const float*)d_in[15];
    const float* l2_is_relW  = (const float*)d_in[16];
    const float* l2_is_relb  = (const float*)d_in[17];
    const float* l2_is_rootW = (const float*)d_in[18];
    const float* l2_rev_relW = (const float*)d_in[19];
    const float* l2_rev_relb = (const float*)d_in[20];
    const float* l2_rev_rootW= (const float*)d_in[21];

    char* ws = (char*)d_ws;
    size_t off = 0;
    auto alloc = [&](size_t bytes) {
        char* p = ws + off;
        off += (bytes + 255) & ~(size_t)255;
        return p;
    };
    __hip_bfloat16* xp_bf = (__hip_bfloat16*)alloc((size_t)N_PAPER * 128 * 2);
    __hip_bfloat16* hp1   = (__hip_bfloat16*)alloc((size_t)N_PAPER * 128 * 2);
    __hip_bfloat16* Hg    = (__hip_bfloat16*)alloc((size_t)N_PAPER * 128 * 2);
    __hip_bfloat16* Hr    = (__hip_bfloat16*)alloc((size_t)N_PAPER * 128 * 2);
    unsigned* ebuf_c = (unsigned*)alloc((size_t)E_CITES * 4);
    int*      col_c  = (int*)alloc((size_t)E_CITES * 4);
    unsigned* ebuf_r = (unsigned*)alloc((size_t)E_IS * 4);
    int*      col_r  = (int*)alloc((size_t)E_IS * 4);
    unsigned* ebuf_l = (unsigned*)alloc((size_t)E_IS * 4);
    int*   rp_c  = (int*)alloc((size_t)(N_PAPER + 1) * 4);
    int*   rp_r  = (int*)alloc((size_t)(N_PAPER + 1) * 4);
    int*   rp_l  = (int*)alloc((size_t)(N_LABEL + 1) * 4);
    int*   bhist_c = (int*)alloc((size_t)(NBKT + NBKT + 128) * 4);
    int*   bhist_r = bhist_c + NBKT;
    int*   bhist_l = bhist_r + NBKT;
    int*   bbase_c = (int*)alloc((size_t)(NBKT + 1) * 4);
    int*   bcur_c  = (int*)alloc((size_t)NBKT * 4);
    int*   bbase_r = (int*)alloc((size_t)(NBKT + 1) * 4);
    int*   bcur_r  = (int*)alloc((size_t)NBKT * 4);
    int*   bcur_l  = (int*)alloc((size_t)128 * 4);
    float* dinv  = (float*)alloc((size_t)N_PAPER * 4);
    __hip_bfloat16* Wp1 = (__hip_bfloat16*)alloc((size_t)32768 * 2);
    __hip_bfloat16* Wp2 = (__hip_bfloat16*)alloc((size_t)16384 * 2);
    float* yrev1 = (float*)alloc(128 * 128 * 4);
    float* yrev2 = (float*)alloc(128 * 64 * 4);
    float* hl1   = (float*)alloc(128 * 128 * 4);
    float* partialL = (float*)alloc((size_t)N_LABEL * LSPLIT * 128 * 4);

    float* zp = (float*)d_out;                          // [100000 x 64]
    float* zl = (float*)d_out + (size_t)N_PAPER * 64;   // [128 x 64]

    hipMemsetAsync(bhist_c, 0, (size_t)(NBKT + NBKT + 128) * 4, stream);

    // ---- CSR builds (cites by dst, rev-is by paper src, is by label dst) ----
    fused_count<<<NCC + NCR + NCL, 256, 0, stream>>>(cd, iss, isd, bhist_c, bhist_r, bhist_l);
    scan_sums<<<1, 128, 0, stream>>>(bhist_c, bbase_c, bcur_c,
                                     bhist_r, bbase_r, bcur_r,
                                     bhist_l, rp_l, bcur_l);
    fused_scatter<<<NSC + 2 * NSI, 256, 0, stream>>>(cd, cs, iss, isd,
                                                     bcur_c, ebuf_c, bcur_r, ebuf_r, bcur_l, ebuf_l);
    fused_csr<<<2 * NBKT, 1024, 0, stream>>>(ebuf_c, bbase_c, rp_c, col_c, dinv,
                                             ebuf_r, bbase_r, rp_r, col_r);
    fused_prep<<<NCONV + 128 + 64 + 64, 256, 0, stream>>>(
        xp, xp_bf, l1_gcn_W, l1_rev_rootW, Wp1, l2_gcn_W, l2_rev_rootW, Wp2,
        xl, l1_rev_relW, yrev1);

    // ---- layer 1 ----
    gemm_mfma<128><<<(N_PAPER + 63) / 64, 256, 0, stream>>>(xp_bf, Wp1, dinv, Hg, Hr, N_PAPER);
    paper_assemble<128, true, __hip_bfloat16><<<(N_PAPER + 3) / 4, 256, 0, stream>>>(
        Hg, Hr, rp_c, col_c, dinv, rp_r, col_r, yrev1, l1_gcn_b, l1_rev_relb, hp1);
    label_agg<<<dim3(N_LABEL, LSPLIT), 128, 0, stream>>>(xp_bf, rp_l, ebuf_l, partialL);
    label_finish<128, true, true><<<N_LABEL, 128, 0, stream>>>(
        partialL, xl, l1_is_relW, l1_is_rootW, l1_is_relb, hl1, l2_rev_relW, yrev2);

    // ---- layer 2 ----
    gemm_mfma<64><<<(N_PAPER + 63) / 64, 256, 0, stream>>>(hp1, Wp2, dinv, Hg, Hr, N_PAPER);
    paper_assemble<64, false, float><<<(N_PAPER + 3) / 4, 256, 0, stream>>>(
        Hg, Hr, rp_c, col_c, dinv, rp_r, col_r, yrev2, l2_gcn_b, l2_rev_relb, zp);
    label_agg<<<dim3(N_LABEL, LSPLIT), 128, 0, stream>>>(hp1, rp_l, ebuf_l, partialL);
    label_finish<64, false, false><<<N_LABEL, 128, 0, stream>>>(
        partialL, hl1, l2_is_relW, l2_is_rootW, l2_is_relb, zl, nullptr, nullptr);
}

// Round 9
// 350.737 us; speedup vs baseline: 1.0777x; 1.0777x over previous
//
#include <hip/hip_runtime.h>
#include <hip/hip_bf16.h>

#define N_PAPER 100000
#define N_LABEL 128
#define E_CITES 1600000
#define E_IS    100000
#define NBKT    98   // node>>10 buckets
#define A2_CHUNK 2048
#define LSPLIT  8

typedef __bf16 bf16x8 __attribute__((ext_vector_type(8)));
typedef float  f32x4  __attribute__((ext_vector_type(4)));
typedef float  f32x2  __attribute__((ext_vector_type(2)));

static __device__ __forceinline__ float bf_lo(unsigned u) {
    union { unsigned u; float f; } v; v.u = u << 16; return v.f;
}
static __device__ __forceinline__ float bf_hi(unsigned u) {
    union { unsigned u; float f; } v; v.u = u & 0xffff0000u; return v.f;
}
static __device__ __forceinline__ unsigned pk_bf(float a, float b) {
    __hip_bfloat16 x = __float2bfloat16(a), y = __float2bfloat16(b);
    unsigned short ux = *(unsigned short*)&x, uy = *(unsigned short*)&y;
    return (unsigned)ux | ((unsigned)uy << 16);
}
// fp8 e4m3 (OCP on gfx950) encode/decode via HW cvt
static __device__ __forceinline__ unsigned char enc_fp8(float v) {
    return (unsigned char)(__builtin_amdgcn_cvt_pk_fp8_f32(v, v, 0, false) & 0xFF);
}
static __device__ __forceinline__ void dec_add4(unsigned u, float* acc) {
    f32x2 a = __builtin_amdgcn_cvt_pk_f32_fp8((int)u, false);
    f32x2 b = __builtin_amdgcn_cvt_pk_f32_fp8((int)u, true);
    acc[0] += a[0]; acc[1] += a[1]; acc[2] += b[0]; acc[3] += b[1];
}
static __device__ __forceinline__ void dec4(unsigned u, float* o) {
    f32x2 a = __builtin_amdgcn_cvt_pk_f32_fp8((int)u, false);
    f32x2 b = __builtin_amdgcn_cvt_pk_f32_fp8((int)u, true);
    o[0] = a[0]; o[1] = a[1]; o[2] = b[0]; o[3] = b[1];
}

// ---------------- fused bucket histograms (cites, rev, label) ----------------
#define NCC 224
#define NCR 32
#define NCL 32
__global__ __launch_bounds__(256) void fused_count(
    const int* __restrict__ cd, const int* __restrict__ iss, const int* __restrict__ isd,
    int* __restrict__ bhist_c, int* __restrict__ bhist_r, int* __restrict__ bhist_l)
{
    __shared__ int h[128];
    int b = blockIdx.x, t = threadIdx.x;
    const int* key; int E, shift, nb, b0, nblk; int* hist;
    if (b < NCC)            { key = cd;  E = E_CITES; hist = bhist_c; shift = 10; nb = NBKT; b0 = b;             nblk = NCC; }
    else if (b < NCC + NCR) { key = iss; E = E_IS;    hist = bhist_r; shift = 10; nb = NBKT; b0 = b - NCC;       nblk = NCR; }
    else                    { key = isd; E = E_IS;    hist = bhist_l; shift = 0;  nb = 128;  b0 = b - NCC - NCR; nblk = NCL; }
    if (t < nb) h[t] = 0;
    __syncthreads();
    for (int i = b0 * 256 + t; i < E; i += nblk * 256)
        atomicAdd(&h[key[i] >> shift], 1);
    __syncthreads();
    if (t < nb && h[t]) atomicAdd(&hist[t], h[t]);
}

// single block: exclusive-scan three histograms (cites 98, rev 98, label 128)
__global__ __launch_bounds__(128) void scan_sums(
    const int* __restrict__ bhist_c, int* __restrict__ bbase_c, int* __restrict__ bcur_c,
    const int* __restrict__ bhist_r, int* __restrict__ bbase_r, int* __restrict__ bcur_r,
    const int* __restrict__ bhist_l, int* __restrict__ rp_l, int* __restrict__ bcur_l)
{
    __shared__ int sh[3][128];
    int t = threadIdx.x;
    sh[0][t] = (t < NBKT) ? bhist_c[t] : 0;
    sh[1][t] = (t < NBKT) ? bhist_r[t] : 0;
    sh[2][t] = bhist_l[t];
    __syncthreads();
    for (int off = 1; off < 128; off <<= 1) {
        int v0 = (t >= off) ? sh[0][t - off] : 0;
        int v1 = (t >= off) ? sh[1][t - off] : 0;
        int v2 = (t >= off) ? sh[2][t - off] : 0;
        __syncthreads();
        sh[0][t] += v0; sh[1][t] += v1; sh[2][t] += v2;
        __syncthreads();
    }
    if (t < NBKT) {
        int b = (t == 0) ? 0 : sh[0][t - 1];
        bbase_c[t] = b; bcur_c[t] = b;
        if (t == NBKT - 1) bbase_c[NBKT] = sh[0][t];
        int b2 = (t == 0) ? 0 : sh[1][t - 1];
        bbase_r[t] = b2; bcur_r[t] = b2;
        if (t == NBKT - 1) bbase_r[NBKT] = sh[1][t];
    }
    int b3 = (t == 0) ? 0 : sh[2][t - 1];
    rp_l[t] = b3; bcur_l[t] = b3;
    if (t == 127) rp_l[128] = sh[2][127];
}

// ---------------- fused bucketed edge scatter (packed u32) ----------------
// ebuf[p] = ((key & 1023) << 17) | val   (val < 2^17)
#define NSC ((E_CITES + A2_CHUNK - 1) / A2_CHUNK)
#define NSI ((E_IS + A2_CHUNK - 1) / A2_CHUNK)
__global__ __launch_bounds__(256) void fused_scatter(
    const int* __restrict__ cd, const int* __restrict__ cs,
    const int* __restrict__ iss, const int* __restrict__ isd,
    int* __restrict__ bcur_c, unsigned* __restrict__ ebuf_c,
    int* __restrict__ bcur_r, unsigned* __restrict__ ebuf_r,
    int* __restrict__ bcur_l, unsigned* __restrict__ ebuf_l)
{
    __shared__ int sk[A2_CHUNK], sv[A2_CHUNK];
    __shared__ int h[128], base[128], cur[128];
    int b = blockIdx.x, t = threadIdx.x;
    const int* key; const int* val; int E, shift, b0; int* bcur; unsigned* ebuf;
    if (b < NSC)            { key = cd;  val = cs;  E = E_CITES; bcur = bcur_c; ebuf = ebuf_c; shift = 10; b0 = b; }
    else if (b < NSC + NSI) { key = iss; val = isd; E = E_IS;    bcur = bcur_r; ebuf = ebuf_r; shift = 10; b0 = b - NSC; }
    else                    { key = isd; val = iss; E = E_IS;    bcur = bcur_l; ebuf = ebuf_l; shift = 0;  b0 = b - NSC - NSI; }
    int e0 = b0 * A2_CHUNK;
    int n = min(A2_CHUNK, E - e0);
    for (int i = t; i < 128; i += 256) h[i] = 0;
    __syncthreads();
    for (int i = t; i < n; i += 256) {
        int k = key[e0 + i], v = val[e0 + i];
        sk[i] = k; sv[i] = v;
        atomicAdd(&h[k >> shift], 1);
    }
    __syncthreads();
    for (int i = t; i < 128; i += 256) { base[i] = atomicAdd(&bcur[i], h[i]); cur[i] = 0; }
    __syncthreads();
    for (int i = t; i < n; i += 256) {
        int bb = sk[i] >> shift;
        int p = base[bb] + atomicAdd(&cur[bb], 1);
        ebuf[p] = ((unsigned)(sk[i] & 1023) << 17) | (unsigned)sv[i];
    }
}

// ---------------- fused per-bucket CSR build (cites + rev) ----------------
__global__ __launch_bounds__(1024) void fused_csr(
    const unsigned* __restrict__ ebuf_c, const int* __restrict__ bbase_c,
    int* __restrict__ rp_c, int* __restrict__ col_c, float* __restrict__ dinv,
    const unsigned* __restrict__ ebuf_r, const int* __restrict__ bbase_r,
    int* __restrict__ rp_r, int* __restrict__ col_r)
{
    __shared__ int hist[1024];
    __shared__ int sc[1024];
    int bb = blockIdx.x, t = threadIdx.x;
    const unsigned* ebuf; const int* bbase; int* rp; int* col; float* dv; int b;
    if (bb < NBKT) { ebuf = ebuf_c; bbase = bbase_c; rp = rp_c; col = col_c; dv = dinv; b = bb; }
    else           { ebuf = ebuf_r; bbase = bbase_r; rp = rp_r; col = col_r; dv = nullptr; b = bb - NBKT; }
    int s = bbase[b], e = bbase[b + 1];
    hist[t] = 0;
    __syncthreads();
    for (int i = s + t; i < e; i += 1024)
        atomicAdd(&hist[ebuf[i] >> 17], 1);
    __syncthreads();
    int v = hist[t];
    sc[t] = v;
    __syncthreads();
    for (int off = 1; off < 1024; off <<= 1) {
        int u = (t >= off) ? sc[t - off] : 0;
        __syncthreads();
        sc[t] += u;
        __syncthreads();
    }
    int excl = sc[t] - v;
    int node = b * 1024 + t;
    if (node < N_PAPER) {
        rp[node] = s + excl;
        if (dv) dv[node] = rsqrtf((float)v + 1.0f);
        if (node == N_PAPER - 1) rp[N_PAPER] = s + excl + v;
    }
    __syncthreads();
    hist[t] = s + excl;   // reuse as running cursor
    __syncthreads();
    for (int i = s + t; i < e; i += 1024) {
        unsigned u = ebuf[i];
        int p = atomicAdd(&hist[u >> 17], 1);
        col[p] = (int)(u & 0x1FFFFu);
    }
}

// ---------------- fused prep: conv_bf16 + pack_wp(1,2) + yrev1 small_mm -----
#define NCONV 12500   // 100000*128/4 / 256
__global__ __launch_bounds__(256) void fused_prep(
    const float* __restrict__ xp, __hip_bfloat16* __restrict__ xp_bf,
    const float* __restrict__ g1, const float* __restrict__ r1, __hip_bfloat16* __restrict__ Wp1,
    const float* __restrict__ g2, const float* __restrict__ r2, __hip_bfloat16* __restrict__ Wp2,
    const float* __restrict__ xl, const float* __restrict__ W1rev, float* __restrict__ yrev1)
{
    int b = blockIdx.x, t = threadIdx.x;
    if (b < NCONV) {
        int i = b * 256 + t;
        const int n4 = N_PAPER * 128 / 4;
        if (i < n4) {
            float4 v = *(const float4*)(xp + (size_t)i * 4);
            __hip_bfloat16* o = xp_bf + (size_t)i * 4;
            o[0] = __float2bfloat16(v.x); o[1] = __float2bfloat16(v.y);
            o[2] = __float2bfloat16(v.z); o[3] = __float2bfloat16(v.w);
        }
        return;
    }
    if (b < NCONV + 128 + 64) {
        bool big = (b < NCONV + 128);
        const float* g = big ? g1 : g2;
        const float* r = big ? r1 : r2;
        __hip_bfloat16* Wp = big ? Wp1 : Wp2;
        int DG = big ? 128 : 64;
        int i = (big ? (b - NCONV) : (b - NCONV - 128)) * 256 + t;
        int j    = i & 7;
        int lane = (i >> 3) & 63;
        int ks   = (i >> 9) & 3;
        int nt   = i >> 11;
        int k = ks * 32 + (lane >> 4) * 8 + j;
        int c = nt * 16 + (lane & 15);
        float v = (c < DG) ? g[k * DG + c] : r[k * DG + (c - DG)];
        Wp[i] = __float2bfloat16(v);
        return;
    }
    // yrev1: 64 blocks, 2 labels per block
    __shared__ float xrow[2][128];
    int bb = b - (NCONV + 128 + 64);
    int half = t >> 7, tt = t & 127;
    int l = bb * 2 + half;
    xrow[half][tt] = xl[(size_t)l * 128 + tt];
    __syncthreads();
    float o = 0.f;
    for (int k = 0; k < 128; ++k) o = fmaf(xrow[half][k], W1rev[k * 128 + tt], o);
    yrev1[(size_t)l * 128 + tt] = o;
}

// ---------------- MFMA GEMM: Hg = fp8(dinv.*(A@Wg)), Hr = bf16(A@Wr) --------
template<int DG>
__global__ __launch_bounds__(256) void gemm_mfma(
    const __hip_bfloat16* __restrict__ A, const __hip_bfloat16* __restrict__ Wp,
    const float* __restrict__ dinv,
    unsigned char* __restrict__ Hg, __hip_bfloat16* __restrict__ Hr, int M)
{
    constexpr int NT2 = 2 * DG / 16;
    int tid = threadIdx.x;
    int wv = tid >> 6, lane = tid & 63;
    int m0 = blockIdx.x * 64 + wv * 16;
    int row = m0 + (lane & 15);
    int rowc = min(row, M - 1);
    int kg = lane >> 4;

    bf16x8 a[4];
    const __hip_bfloat16* ap = A + (size_t)rowc * 128 + kg * 8;
    #pragma unroll
    for (int ks = 0; ks < 4; ++ks)
        a[ks] = *(const bf16x8*)(ap + ks * 32);

    f32x4 acc[NT2] = {};
    #pragma unroll
    for (int ks = 0; ks < 4; ++ks) {
        #pragma unroll
        for (int nt = 0; nt < NT2; ++nt) {
            bf16x8 b = *(const bf16x8*)(Wp + ((size_t)(nt * 4 + ks) * 64 + lane) * 8);
            acc[nt] = __builtin_amdgcn_mfma_f32_16x16x32_bf16(a[ks], b, acc[nt], 0, 0, 0);
        }
    }

    int rbase = m0 + (lane >> 4) * 4;
    int c = lane & 15;
    float ds[4];
    #pragma unroll
    for (int r = 0; r < 4; ++r) {
        int rr = rbase + r;
        ds[r] = (rr < M) ? dinv[rr] : 1.f;
    }
    #pragma unroll
    for (int nt = 0; nt < NT2; ++nt) {
        bool isG = (nt < DG / 16);
        if (isG) {
            int cc = nt * 16 + c;
            #pragma unroll
            for (int r = 0; r < 4; ++r) {
                int rr = rbase + r;
                if (rr < M) Hg[(size_t)rr * DG + cc] = enc_fp8(acc[nt][r] * ds[r]);
            }
        } else {
            int cc = (nt - DG / 16) * 16 + c;
            #pragma unroll
            for (int r = 0; r < 4; ++r) {
                int rr = rbase + r;
                if (rr < M) Hr[(size_t)rr * DG + cc] = __float2bfloat16(acc[nt][r]);
            }
        }
    }
}

// ---------------- fused paper-side assembly (fp8 Hg pre-scaled, bf16 Hr) ----
// Round-7 structure: stride-4 groups, 2-deep unroll, late self loads.
template<int D, bool RELU, typename OutT>
__global__ __launch_bounds__(256) void paper_assemble(
    const unsigned char* __restrict__ Hg, const __hip_bfloat16* __restrict__ Hr,
    const int* __restrict__ rp_c, const int* __restrict__ col_c,
    const float* __restrict__ dinv,
    const int* __restrict__ rp_r, const int* __restrict__ col_r,
    const float* __restrict__ yrev,
    const float* __restrict__ gcn_b, const float* __restrict__ rev_relb,
    OutT* __restrict__ out)
{
    constexpr int NB = D / 16;  // dims (and bytes) per lane: 8 (D=128) or 4 (D=64)
    int w = (int)((blockIdx.x * 256 + threadIdx.x) >> 6);
    if (w >= N_PAPER) return;
    int lane = threadIdx.x & 63;
    int grp = lane >> 4, sub = lane & 15;
    int d0 = sub * NB;
    float acc[NB] = {};
    int s = rp_c[w], e = rp_c[w + 1];
    int j = s + grp;
    for (; j + 4 < e; j += 8) {
        int src0 = col_c[j];
        int src1 = col_c[j + 4];
        const unsigned char* p0 = Hg + (size_t)src0 * D + d0;
        const unsigned char* p1 = Hg + (size_t)src1 * D + d0;
        if constexpr (NB == 8) {
            uint2 u = *(const uint2*)p0;
            uint2 v = *(const uint2*)p1;
            dec_add4(u.x, acc); dec_add4(u.y, acc + 4);
            dec_add4(v.x, acc); dec_add4(v.y, acc + 4);
        } else {
            unsigned u = *(const unsigned*)p0;
            unsigned v = *(const unsigned*)p1;
            dec_add4(u, acc); dec_add4(v, acc);
        }
    }
    if (j < e) {
        const unsigned char* p = Hg + (size_t)col_c[j] * D + d0;
        if constexpr (NB == 8) {
            uint2 u = *(const uint2*)p;
            dec_add4(u.x, acc); dec_add4(u.y, acc + 4);
        } else {
            unsigned u = *(const unsigned*)p;
            dec_add4(u, acc);
        }
    }
    #pragma unroll
    for (int k = 0; k < NB; ++k) {
        acc[k] += __shfl_xor(acc[k], 16);
        acc[k] += __shfl_xor(acc[k], 32);
    }
    if (grp != 0) return;

    float di = dinv[w];
    float res[NB];
    float sg[NB], sr[NB];
    const unsigned char* hg = Hg + (size_t)w * D + d0;
    const __hip_bfloat16* hr = Hr + (size_t)w * D + d0;
    if constexpr (NB == 8) {
        uint2 ug = *(const uint2*)hg;
        dec4(ug.x, sg); dec4(ug.y, sg + 4);
        uint4 ur = *(const uint4*)hr;
        sr[0] = bf_lo(ur.x); sr[1] = bf_hi(ur.x); sr[2] = bf_lo(ur.y); sr[3] = bf_hi(ur.y);
        sr[4] = bf_lo(ur.z); sr[5] = bf_hi(ur.z); sr[6] = bf_lo(ur.w); sr[7] = bf_hi(ur.w);
    } else {
        unsigned ug = *(const unsigned*)hg;
        dec4(ug, sg);
        uint2 ur = *(const uint2*)hr;
        sr[0] = bf_lo(ur.x); sr[1] = bf_hi(ur.x); sr[2] = bf_lo(ur.y); sr[3] = bf_hi(ur.y);
    }
    #pragma unroll
    for (int k = 0; k < NB; ++k)
        res[k] = di * (acc[k] + sg[k]) + sr[k] + gcn_b[d0 + k] + rev_relb[d0 + k];

    int s2 = rp_r[w], e2 = rp_r[w + 1];
    for (int jj = s2; jj < e2; ++jj) {
        const float* yr = yrev + (size_t)col_r[jj] * D + d0;
        #pragma unroll
        for (int k = 0; k < NB; ++k) res[k] += yr[k];
    }
    #pragma unroll
    for (int k = 0; k < NB; ++k) {
        res[k] *= 0.5f;
        if (RELU) res[k] = fmaxf(res[k], 0.f);
    }
    if constexpr (sizeof(OutT) == 2) {
        if constexpr (NB == 8) {
            uint4 o = make_uint4(pk_bf(res[0], res[1]), pk_bf(res[2], res[3]),
                                 pk_bf(res[4], res[5]), pk_bf(res[6], res[7]));
            *(uint4*)(out + (size_t)w * D + d0) = o;
        } else {
            uint2 o = make_uint2(pk_bf(res[0], res[1]), pk_bf(res[2], res[3]));
            *(uint2*)(out + (size_t)w * D + d0) = o;
        }
    } else {
        if constexpr (NB == 8) {
            *(float4*)((float*)out + (size_t)w * D + d0) =
                make_float4(res[0], res[1], res[2], res[3]);
            *(float4*)((float*)out + (size_t)w * D + d0 + 4) =
                make_float4(res[4], res[5], res[6], res[7]);
        } else {
            *(float4*)((float*)out + (size_t)w * D + d0) =
                make_float4(res[0], res[1], res[2], res[3]);
        }
    }
}

// ---------------- label-side aggregation (grid: 128 labels x LSPLIT) --------
__global__ __launch_bounds__(128) void label_agg(
    const __hip_bfloat16* __restrict__ Xsrc,
    const int* __restrict__ rp_l, const unsigned* __restrict__ ebuf_l,
    float* __restrict__ partialL)
{
    int l = blockIdx.x, sp = blockIdx.y, t = threadIdx.x;
    int s = rp_l[l], e = rp_l[l + 1];
    int n = e - s;
    int per = (n + LSPLIT - 1) / LSPLIT;
    int b = s + sp * per;
    int en = min(b + per, e);
    float acc = 0.f;
    for (int m = b; m < en; ++m)
        acc += __bfloat162float(Xsrc[(size_t)(ebuf_l[m] & 0x1FFFFu) * 128 + t]);
    partialL[((size_t)l * LSPLIT + sp) * 128 + t] = acc;
}

// ---------------- label-side finish: sum partials + tiny GEMM (+ yrev2) -----
template<int DOUT, bool RELU, bool YREV2>
__global__ __launch_bounds__(128) void label_finish(
    const float* __restrict__ partialL, const float* __restrict__ Xdst,
    const float* __restrict__ relW, const float* __restrict__ rootW,
    const float* __restrict__ relb, float* __restrict__ out,
    const float* __restrict__ W2rev, float* __restrict__ yrev2)
{
    __shared__ float arow[128];
    __shared__ float xrow[128];
    __shared__ float hrow[128];
    int l = blockIdx.x, t = threadIdx.x;
    float a = 0.f;
    #pragma unroll
    for (int sp = 0; sp < LSPLIT; ++sp)
        a += partialL[((size_t)l * LSPLIT + sp) * 128 + t];
    arow[t] = a;
    xrow[t] = Xdst[(size_t)l * 128 + t];
    __syncthreads();
    float o = 0.f;
    if (t < DOUT) {
        o = relb[t];
        for (int k = 0; k < 128; ++k)
            o = fmaf(arow[k], relW[k * DOUT + t], fmaf(xrow[k], rootW[k * DOUT + t], o));
        if (RELU) o = fmaxf(o, 0.f);
        out[(size_t)l * DOUT + t] = o;
    }
    if constexpr (YREV2) {
        hrow[t] = o;           // DOUT == 128 here
        __syncthreads();
        if (t < 64) {
            float y = 0.f;
            for (int k = 0; k < 128; ++k)
                y = fmaf(hrow[k], W2rev[k * 64 + t], y);
            yrev2[(size_t)l * 64 + t] = y;
        }
    }
}

extern "C" void kernel_launch(void* const* d_in, const int* in_sizes, int n_in,
                              void* d_out, int out_size, void* d_ws, size_t ws_size,
                              hipStream_t stream)
{
    const float* xp          = (const float*)d_in[0];
    const float* xl          = (const float*)d_in[1];
    const int*   cs          = (const int*)d_in[2];
    const int*   cd          = (const int*)d_in[3];
    const int*   iss         = (const int*)d_in[4];
    const int*   isd         = (const int*)d_in[5];
    const float* l1_gcn_W    = (const float*)d_in[6];
    const float* l1_gcn_b    = (const float*)d_in[7];
    const float* l1_is_relW  = (const float*)d_in[8];
    const float* l1_is_relb  = (const float*)d_in[9];
    const float* l1_is_rootW = (const float*)d_in[10];
    const float* l1_rev_relW = (const float*)d_in[11];
    const float* l1_rev_relb = (const float*)d_in[12];
    const float* l1_rev_rootW= (const float*)d_in[13];
    const float* l2_gcn_W    = (const float*)d_in[14];
    const float* l2_gcn_b    = (const float*)d_in[15];
    const float* l2_is_relW  = (const float*)d_in[16];
    const float* l2_is_relb  = (const float*)d_in[17];
    const float* l2_is_rootW = (const float*)d_in[18];
    const float* l2_rev_relW = (const float*)d_in[19];
    const float* l2_rev_relb = (const float*)d_in[20];
    const float* l2_rev_rootW= (const float*)d_in[21];

    char* ws = (char*)d_ws;
    size_t off = 0;
    auto alloc = [&](size_t bytes) {
        char* p = ws + off;
        off += (bytes + 255) & ~(size_t)255;
        return p;
    };
    __hip_bfloat16* xp_bf = (__hip_bfloat16*)alloc((size_t)N_PAPER * 128 * 2);
    __hip_bfloat16* hp1   = (__hip_bfloat16*)alloc((size_t)N_PAPER * 128 * 2);
    unsigned char*  Hg    = (unsigned char*)alloc((size_t)N_PAPER * 128);
    __hip_bfloat16* Hr    = (__hip_bfloat16*)alloc((size_t)N_PAPER * 128 * 2);
    unsigned* ebuf_c = (unsigned*)alloc((size_t)E_CITES * 4);
    int*      col_c  = (int*)alloc((size_t)E_CITES * 4);
    unsigned* ebuf_r = (unsigned*)alloc((size_t)E_IS * 4);
    int*      col_r  = (int*)alloc((size_t)E_IS * 4);
    unsigned* ebuf_l = (unsigned*)alloc((size_t)E_IS * 4);
    int*   rp_c  = (int*)alloc((size_t)(N_PAPER + 1) * 4);
    int*   rp_r  = (int*)alloc((size_t)(N_PAPER + 1) * 4);
    int*   rp_l  = (int*)alloc((size_t)(N_LABEL + 1) * 4);
    int*   bhist_c = (int*)alloc((size_t)(NBKT + NBKT + 128) * 4);
    int*   bhist_r = bhist_c + NBKT;
    int*   bhist_l = bhist_r + NBKT;
    int*   bbase_c = (int*)alloc((size_t)(NBKT + 1) * 4);
    int*   bcur_c  = (int*)alloc((size_t)NBKT * 4);
    int*   bbase_r = (int*)alloc((size_t)(NBKT + 1) * 4);
    int*   bcur_r  = (int*)alloc((size_t)NBKT * 4);
    int*   bcur_l  = (int*)alloc((size_t)128 * 4);
    float* dinv  = (float*)alloc((size_t)N_PAPER * 4);
    __hip_bfloat16* Wp1 = (__hip_bfloat16*)alloc((size_t)32768 * 2);
    __hip_bfloat16* Wp2 = (__hip_bfloat16*)alloc((size_t)16384 * 2);
    float* yrev1 = (float*)alloc(128 * 128 * 4);
    float* yrev2 = (float*)alloc(128 * 64 * 4);
    float* hl1   = (float*)alloc(128 * 128 * 4);
    float* partialL = (float*)alloc((size_t)N_LABEL * LSPLIT * 128 * 4);

    float* zp = (float*)d_out;                          // [100000 x 64]
    float* zl = (float*)d_out + (size_t)N_PAPER * 64;   // [128 x 64]

    hipMemsetAsync(bhist_c, 0, (size_t)(NBKT + NBKT + 128) * 4, stream);

    // ---- CSR builds (cites by dst, rev-is by paper src, is by label dst) ----
    fused_count<<<NCC + NCR + NCL, 256, 0, stream>>>(cd, iss, isd, bhist_c, bhist_r, bhist_l);
    scan_sums<<<1, 128, 0, stream>>>(bhist_c, bbase_c, bcur_c,
                                     bhist_r, bbase_r, bcur_r,
                                     bhist_l, rp_l, bcur_l);
    fused_scatter<<<NSC + 2 * NSI, 256, 0, stream>>>(cd, cs, iss, isd,
                                                     bcur_c, ebuf_c, bcur_r, ebuf_r, bcur_l, ebuf_l);
    fused_csr<<<2 * NBKT, 1024, 0, stream>>>(ebuf_c, bbase_c, rp_c, col_c, dinv,
                                             ebuf_r, bbase_r, rp_r, col_r);
    fused_prep<<<NCONV + 128 + 64 + 64, 256, 0, stream>>>(
        xp, xp_bf, l1_gcn_W, l1_rev_rootW, Wp1, l2_gcn_W, l2_rev_rootW, Wp2,
        xl, l1_rev_relW, yrev1);

    // ---- layer 1 ----
    gemm_mfma<128><<<(N_PAPER + 63) / 64, 256, 0, stream>>>(xp_bf, Wp1, dinv, Hg, Hr, N_PAPER);
    paper_assemble<128, true, __hip_bfloat16><<<(N_PAPER + 3) / 4, 256, 0, stream>>>(
        Hg, Hr, rp_c, col_c, dinv, rp_r, col_r, yrev1, l1_gcn_b, l1_rev_relb, hp1);
    label_agg<<<dim3(N_LABEL, LSPLIT), 128, 0, stream>>>(xp_bf, rp_l, ebuf_l, partialL);
    label_finish<128, true, true><<<N_LABEL, 128, 0, stream>>>(
        partialL, xl, l1_is_relW, l1_is_rootW, l1_is_relb, hl1, l2_rev_relW, yrev2);

    // ---- layer 2 ----
    gemm_mfma<64><<<(N_PAPER + 63) / 64, 256, 0, stream>>>(hp1, Wp2, dinv, Hg, Hr, N_PAPER);
    paper_assemble<64, false, float><<<(N_PAPER + 3) / 4, 256, 0, stream>>>(
        Hg, Hr, rp_c, col_c, dinv, rp_r, col_r, yrev2, l2_gcn_b, l2_rev_relb, zp);
    label_agg<<<dim3(N_LABEL, LSPLIT), 128, 0, stream>>>(hp1, rp_l, ebuf_l, partialL);
    label_finish<64, false, false><<<N_LABEL, 128, 0, stream>>>(
        partialL, hl1, l2_is_relW, l2_is_rootW, l2_is_relb, zl, nullptr, nullptr);
}